// Round 1
// baseline (3926.798 us; speedup 1.0000x reference)
//
#include <hip/hip_runtime.h>
#include <hip/hip_bf16.h>
#include <math.h>

#define B 256
#define S 128
#define I_DIM 512
#define H 1024
#define C 10
#define FH 4096    // 4*H
#define WROW 1536  // I+H

typedef float f32x4 __attribute__((ext_vector_type(4)));
typedef __bf16 bf16x8 __attribute__((ext_vector_type(8)));

// ---------------- prep kernels ----------------

// whT[d][n][k] = bf16(W_d[n][I_DIM + k]),  [2][4096][1024]
__global__ void wh_convert(const float* __restrict__ fwd_W,
                           const float* __restrict__ bwd_W,
                           __hip_bfloat16* __restrict__ whT) {
    const int total = 2 * FH * H;
    for (int idx = blockIdx.x * blockDim.x + threadIdx.x; idx < total;
         idx += gridDim.x * blockDim.x) {
        int d = idx / (FH * H);
        int r = idx - d * (FH * H);
        int n = r >> 10;          // /H
        int k = r & (H - 1);
        const float* W = d ? bwd_W : fwd_W;
        whT[idx] = __float2bfloat16(W[n * WROW + I_DIM + k]);
    }
}

// projT[d][v][n] = embed[v] . Wx_d[n] + b_d[n],  [2][128][4096] f32
__global__ void proj_kernel(const float* __restrict__ embed,
                            const float* __restrict__ fwd_W,
                            const float* __restrict__ fwd_b,
                            const float* __restrict__ bwd_W,
                            const float* __restrict__ bwd_b,
                            float* __restrict__ projT) {
    __shared__ float wrows[16][516];  // padded stride to dodge bank conflicts
    int d  = blockIdx.x >> 8;   // 512 blocks: 0..255 -> d=0, 256..511 -> d=1
    int nc = blockIdx.x & 255;
    int n0 = nc * 16;
    const float* W    = d ? bwd_W : fwd_W;
    const float* bias = d ? bwd_b : fwd_b;
    int tid = threadIdx.x;
    for (int idx = tid; idx < 16 * 512; idx += 256) {
        int r = idx >> 9, k = idx & 511;
        wrows[r][k] = W[(n0 + r) * WROW + k];
    }
    __syncthreads();
    for (int o = tid; o < 128 * 16; o += 256) {
        int v = o >> 4, r = o & 15;
        const float* er = embed + v * I_DIM;
        float s = bias[n0 + r];
        for (int k = 0; k < I_DIM; k++) s += er[k] * wrows[r][k];
        projT[((d << 7) + v) * FH + n0 + r] = s;
    }
}

// zero-init c, h_f32, h_bf16
__global__ void init_state(float* __restrict__ c, float* __restrict__ hf,
                           __hip_bfloat16* __restrict__ hb) {
    const int total = 2 * B * H;
    for (int i = blockIdx.x * blockDim.x + threadIdx.x; i < total;
         i += gridDim.x * blockDim.x) {
        c[i]  = 0.0f;
        hf[i] = 0.0f;
        hb[i] = __float2bfloat16(0.0f);
    }
}

// ---------------- per-step kernels ----------------

// z[d][b][n] = h_bf16[d][b][:] . whT[d][n][:]   (f32 accumulate via MFMA)
// grid: 256 blocks (bid>>7 = dir, 4 M-tiles x 32 N-tiles), 256 threads (4 waves 2x2)
__global__ __launch_bounds__(256) void gemm_step(
        const __hip_bfloat16* __restrict__ hbf,
        const __hip_bfloat16* __restrict__ whT,
        float* __restrict__ z) {
    int bid  = blockIdx.x;
    int d    = bid >> 7;
    int rem  = bid & 127;
    int mt   = rem >> 5;   // 0..3
    int nt   = rem & 31;   // 0..31
    int wid  = threadIdx.x >> 6;
    int lane = threadIdx.x & 63;
    int wr = wid >> 1, wc = wid & 1;
    int m0 = mt * 64 + wr * 32;
    int n0 = nt * 128 + wc * 64;
    int ar = lane & 15;
    int kg = lane >> 4;

    const __hip_bfloat16* hb = hbf + d * (B * H);
    const __hip_bfloat16* wb = whT + (size_t)d * FH * H;

    f32x4 acc[2][4] = {};

#pragma unroll 2
    for (int k0 = 0; k0 < H; k0 += 32) {
        int ko = k0 + kg * 8;
        bf16x8 a0 = *reinterpret_cast<const bf16x8*>(hb + (m0 + ar) * H + ko);
        bf16x8 a1 = *reinterpret_cast<const bf16x8*>(hb + (m0 + 16 + ar) * H + ko);
        bf16x8 b0 = *reinterpret_cast<const bf16x8*>(wb + (size_t)(n0 + ar) * H + ko);
        bf16x8 b1 = *reinterpret_cast<const bf16x8*>(wb + (size_t)(n0 + 16 + ar) * H + ko);
        bf16x8 b2 = *reinterpret_cast<const bf16x8*>(wb + (size_t)(n0 + 32 + ar) * H + ko);
        bf16x8 b3 = *reinterpret_cast<const bf16x8*>(wb + (size_t)(n0 + 48 + ar) * H + ko);
        acc[0][0] = __builtin_amdgcn_mfma_f32_16x16x32_bf16(a0, b0, acc[0][0], 0, 0, 0);
        acc[0][1] = __builtin_amdgcn_mfma_f32_16x16x32_bf16(a0, b1, acc[0][1], 0, 0, 0);
        acc[0][2] = __builtin_amdgcn_mfma_f32_16x16x32_bf16(a0, b2, acc[0][2], 0, 0, 0);
        acc[0][3] = __builtin_amdgcn_mfma_f32_16x16x32_bf16(a0, b3, acc[0][3], 0, 0, 0);
        acc[1][0] = __builtin_amdgcn_mfma_f32_16x16x32_bf16(a1, b0, acc[1][0], 0, 0, 0);
        acc[1][1] = __builtin_amdgcn_mfma_f32_16x16x32_bf16(a1, b1, acc[1][1], 0, 0, 0);
        acc[1][2] = __builtin_amdgcn_mfma_f32_16x16x32_bf16(a1, b2, acc[1][2], 0, 0, 0);
        acc[1][3] = __builtin_amdgcn_mfma_f32_16x16x32_bf16(a1, b3, acc[1][3], 0, 0, 0);
    }

    // C/D layout (HW-verified): col = lane&15, row = (lane>>4)*4 + reg
    float* zb = z + (size_t)d * B * FH;
    int orow = (lane >> 4) * 4;
    int ocol = lane & 15;
#pragma unroll
    for (int i = 0; i < 2; i++)
#pragma unroll
        for (int j = 0; j < 4; j++)
#pragma unroll
            for (int r = 0; r < 4; r++)
                zb[(size_t)(m0 + i * 16 + orow + r) * FH + n0 + j * 16 + ocol] =
                    acc[i][j][r];
}

// gates: z + gathered proj -> nonlinearities -> c,h update
__global__ void gate_step(const float* __restrict__ z,
                          const float* __restrict__ projT,
                          const int* __restrict__ x,
                          float* __restrict__ c, float* __restrict__ hf,
                          __hip_bfloat16* __restrict__ hb, int t) {
    int tid = blockIdx.x * blockDim.x + threadIdx.x;  // 0 .. 2*256*1024
    int d = tid >> 18;
    int r = tid & ((1 << 18) - 1);
    int b = r >> 10;
    int j = r & (H - 1);
    int tt  = d ? (S - 1 - t) : t;
    int idx = x[b * S + tt];
    const float* zr = z + (size_t)d * B * FH + (size_t)b * FH;
    const float* pr = projT + (size_t)((d << 7) + idx) * FH;
    float zg = zr[j]         + pr[j];
    float zi = zr[H + j]     + pr[H + j];
    float zf = zr[2 * H + j] + pr[2 * H + j];
    float zo = zr[3 * H + j] + pr[3 * H + j];
    float g  = tanhf(zg);
    float ii = 1.0f / (1.0f + expf(-zi));
    float ff = 1.0f / (1.0f + expf(-zf));
    float oo = 1.0f / (1.0f + expf(-zo));
    int ci = d * (B * H) + b * H + j;
    float cn = g * ii + c[ci] * ff;
    c[ci] = cn;
    float hn = tanhf(cn) * oo;
    hf[ci] = hn;
    hb[ci] = __float2bfloat16(hn);
}

// ---------------- head ----------------
__global__ void head_kernel(const float* __restrict__ hf,
                            const float* __restrict__ p_w,
                            const float* __restrict__ p_b,
                            float* __restrict__ out) {
    int b = blockIdx.x;
    int lane = threadIdx.x;  // 64
    float part[C];
#pragma unroll
    for (int cc = 0; cc < C; cc++) part[cc] = 0.0f;
    for (int jj = lane; jj < 2 * H; jj += 64) {
        float hv = (jj < H) ? hf[b * H + jj] : hf[B * H + b * H + jj - H];
#pragma unroll
        for (int cc = 0; cc < C; cc++) part[cc] += hv * p_w[cc * 2 * H + jj];
    }
#pragma unroll
    for (int cc = 0; cc < C; cc++) {
        float v = part[cc];
        for (int off = 32; off; off >>= 1) v += __shfl_down(v, off);
        part[cc] = v;
    }
    if (lane == 0) {
        float lg[C];
        float m = -1e30f;
        for (int cc = 0; cc < C; cc++) {
            lg[cc] = part[cc] + p_b[cc];
            m = fmaxf(m, lg[cc]);
        }
        float s = 0.0f;
        for (int cc = 0; cc < C; cc++) s += expf(lg[cc] - m);
        float lse = logf(s) + m;
        for (int cc = 0; cc < C; cc++) out[b * C + cc] = lg[cc] - lse;
    }
}

// ---------------- launch ----------------
extern "C" void kernel_launch(void* const* d_in, const int* in_sizes, int n_in,
                              void* d_out, int out_size, void* d_ws, size_t ws_size,
                              hipStream_t stream) {
    const int*   x     = (const int*)d_in[0];
    const float* embed = (const float*)d_in[1];
    const float* fwd_W = (const float*)d_in[2];
    const float* fwd_b = (const float*)d_in[3];
    const float* bwd_W = (const float*)d_in[4];
    const float* bwd_b = (const float*)d_in[5];
    const float* p_w   = (const float*)d_in[6];
    const float* p_b   = (const float*)d_in[7];
    float* out = (float*)d_out;

    char* ws = (char*)d_ws;
    float* projT = (float*)ws;                 ws += (size_t)2 * 128 * FH * 4;   // 4 MB
    __hip_bfloat16* whT = (__hip_bfloat16*)ws; ws += (size_t)2 * FH * H * 2;     // 16 MB
    float* z  = (float*)ws;                    ws += (size_t)2 * B * FH * 4;     // 8 MB
    float* c  = (float*)ws;                    ws += (size_t)2 * B * H * 4;      // 2 MB
    float* hf = (float*)ws;                    ws += (size_t)2 * B * H * 4;      // 2 MB
    __hip_bfloat16* hb = (__hip_bfloat16*)ws;  ws += (size_t)2 * B * H * 2;      // 1 MB

    hipLaunchKernelGGL(wh_convert, dim3(2048), dim3(256), 0, stream, fwd_W, bwd_W, whT);
    hipLaunchKernelGGL(proj_kernel, dim3(512), dim3(256), 0, stream,
                       embed, fwd_W, fwd_b, bwd_W, bwd_b, projT);
    hipLaunchKernelGGL(init_state, dim3(1024), dim3(256), 0, stream, c, hf, hb);

    for (int t = 0; t < S; t++) {
        hipLaunchKernelGGL(gemm_step, dim3(256), dim3(256), 0, stream, hb, whT, z);
        hipLaunchKernelGGL(gate_step, dim3(2048), dim3(256), 0, stream,
                           z, projT, x, c, hf, hb, t);
    }

    hipLaunchKernelGGL(head_kernel, dim3(B), dim3(64), 0, stream, hf, p_w, p_b, out);
}